// Round 7
// baseline (691.829 us; speedup 1.0000x reference)
//
#include <hip/hip_runtime.h>
#include <hip/hip_bf16.h>
#include <cstdint>

typedef unsigned int uint32;
typedef unsigned short ushort16;
typedef __attribute__((ext_vector_type(8))) short short8;   // 8 bf16 (4 VGPRs)
typedef __attribute__((ext_vector_type(4))) float f32x4;

// fp32 -> bf16 round-to-nearest-even (finite inputs)
__device__ __forceinline__ ushort16 f2bf(float f) {
    uint32 u = __float_as_uint(f);
    u += 0x7fffu + ((u >> 16) & 1u);
    return (ushort16)(u >> 16);
}
__device__ __forceinline__ uint32 packbf2(float lo, float hi) {
    return (uint32)f2bf(lo) | ((uint32)f2bf(hi) << 16);
}
__device__ __forceinline__ float bf_lo(uint32 u) { return __uint_as_float(u << 16); }
__device__ __forceinline__ float bf_hi(uint32 u) { return __uint_as_float(u & 0xffff0000u); }

// ---------------- weight convert + transpose: Wt[n][k] = bf16(W[k][n]) ----------------
__global__ __launch_bounds__(256) void convertW_kernel(
    const float* __restrict__ W1, const float* __restrict__ W2,
    const float* __restrict__ Wl, ushort16* __restrict__ Wt)
{
    const float* src = blockIdx.z == 0 ? W1 : (blockIdx.z == 1 ? W2 : Wl);
    ushort16* dst = Wt + (size_t)blockIdx.z * 512 * 512;
    __shared__ ushort16 tile[32][33];
    const int n0 = blockIdx.x * 32, k0 = blockIdx.y * 32;
    const int tx = threadIdx.x & 31, ty = threadIdx.x >> 5;
    #pragma unroll
    for (int j = 0; j < 32; j += 8)
        tile[ty + j][tx] = f2bf(src[(size_t)(k0 + ty + j) * 512 + n0 + tx]);
    __syncthreads();
    #pragma unroll
    for (int j = 0; j < 32; j += 8)
        dst[(size_t)(n0 + ty + j) * 512 + k0 + tx] = tile[tx][ty + j];
}

// ---------------- CSR build ----------------
__global__ __launch_bounds__(256) void zero_kernel(int* __restrict__ p, int n) {
    int i = blockIdx.x * 256 + threadIdx.x;
    if (i < n) p[i] = 0;
}
__global__ __launch_bounds__(256) void hist_kernel(
    const int* __restrict__ rows, int* __restrict__ deg, int E)
{
    int e = blockIdx.x * 256 + threadIdx.x;
    if (e < E) atomicAdd(&deg[rows[e]], 1);
}
__global__ __launch_bounds__(256) void scan_block_kernel(
    const int* __restrict__ deg, int* __restrict__ offs, int* __restrict__ bsum)
{
    __shared__ int s[256];
    const int t = threadIdx.x, i = blockIdx.x * 256 + t;
    int v = deg[i];
    s[t] = v; __syncthreads();
    for (int off = 1; off < 256; off <<= 1) {
        int x = (t >= off) ? s[t - off] : 0;
        __syncthreads();
        s[t] += x;
        __syncthreads();
    }
    offs[i] = s[t] - v;
    if (t == 255) bsum[blockIdx.x] = s[t];
}
__global__ __launch_bounds__(256) void scan_top_kernel(int* __restrict__ bsum)
{
    __shared__ int s[256];
    const int t = threadIdx.x;
    int v = bsum[t];
    s[t] = v; __syncthreads();
    for (int off = 1; off < 256; off <<= 1) {
        int x = (t >= off) ? s[t - off] : 0;
        __syncthreads();
        s[t] += x;
        __syncthreads();
    }
    bsum[t] = s[t] - v;
}
__global__ __launch_bounds__(256) void scan_add_kernel(
    int* __restrict__ offs, const int* __restrict__ bsum)
{
    offs[blockIdx.x * 256 + threadIdx.x] += bsum[blockIdx.x];
}
__global__ __launch_bounds__(256) void fill_kernel(
    const int* __restrict__ rows, const int* __restrict__ cols,
    const float* __restrict__ vals, const int* __restrict__ offs,
    int* __restrict__ cursor, int* __restrict__ ecol, float* __restrict__ ew, int E)
{
    int e = blockIdx.x * 256 + threadIdx.x;
    if (e >= E) return;
    int r = rows[e];
    int p = atomicAdd(&cursor[r], 1);
    int s = offs[r] + p;
    ecol[s] = cols[e];
    ew[s] = vals[e];
}

// ---- CSR gather on fp32 X -> bf16 aggX: D[row] = Σ w * X[col]  (no bias, no relu) ----
// Linearity: Agg(X@W1) == (Agg X)@W1, so layer-1 gathers BEFORE the GEMM.
__global__ __launch_bounds__(256) void gatherX_kernel(
    const float* __restrict__ X, ushort16* __restrict__ D,
    const int* __restrict__ offs, const int* __restrict__ deg,
    const int* __restrict__ ecol, const float* __restrict__ ew)
{
    const int wave = threadIdx.x >> 6, l = threadIdx.x & 63;
    const int row = blockIdx.x * 4 + wave;
    float acc[8];
    #pragma unroll
    for (int i = 0; i < 8; i++) acc[i] = 0.f;
    const int start = offs[row], d = deg[row];
    for (int j = 0; j < d; j++) {
        int col = ecol[start + j];
        float w = ew[start + j];
        const float4* xr = (const float4*)(X + (size_t)col * 512) + l * 2;
        float4 a = xr[0], b = xr[1];
        acc[0] = fmaf(w, a.x, acc[0]); acc[1] = fmaf(w, a.y, acc[1]);
        acc[2] = fmaf(w, a.z, acc[2]); acc[3] = fmaf(w, a.w, acc[3]);
        acc[4] = fmaf(w, b.x, acc[4]); acc[5] = fmaf(w, b.y, acc[5]);
        acc[6] = fmaf(w, b.z, acc[6]); acc[7] = fmaf(w, b.w, acc[7]);
    }
    uint4 o;
    o.x = packbf2(acc[0], acc[1]);
    o.y = packbf2(acc[2], acc[3]);
    o.z = packbf2(acc[4], acc[5]);
    o.w = packbf2(acc[6], acc[7]);
    ((uint4*)D)[(size_t)row * 64 + l] = o;
}

// ---- CSR gather (bf16 in/out, fp32 accum): D[row]=relu(bias + Σ w*S[col] + Σw*c[g]) ----
__global__ __launch_bounds__(256) void gather_kernel(
    const ushort16* __restrict__ S, ushort16* __restrict__ D,
    const int* __restrict__ offs, const int* __restrict__ deg,
    const int* __restrict__ ecol, const float* __restrict__ ew,
    const float* __restrict__ bias, const float* __restrict__ cadd, int nPerGraph)
{
    const int wave = threadIdx.x >> 6, l = threadIdx.x & 63;
    const int row = blockIdx.x * 4 + wave;
    const uint4* S4 = (const uint4*)S;     // 64 x uint4 per row
    float acc[8];
    {
        float4 b0 = ((const float4*)bias)[l * 2];
        float4 b1 = ((const float4*)bias)[l * 2 + 1];
        acc[0] = b0.x; acc[1] = b0.y; acc[2] = b0.z; acc[3] = b0.w;
        acc[4] = b1.x; acc[5] = b1.y; acc[6] = b1.z; acc[7] = b1.w;
    }
    const int start = offs[row], d = deg[row];
    float sw = 0.f;
    for (int j = 0; j < d; j++) {
        int col = ecol[start + j];
        float w = ew[start + j];
        uint4 s = S4[(size_t)col * 64 + l];
        acc[0] = fmaf(w, bf_lo(s.x), acc[0]); acc[1] = fmaf(w, bf_hi(s.x), acc[1]);
        acc[2] = fmaf(w, bf_lo(s.y), acc[2]); acc[3] = fmaf(w, bf_hi(s.y), acc[3]);
        acc[4] = fmaf(w, bf_lo(s.z), acc[4]); acc[5] = fmaf(w, bf_hi(s.z), acc[5]);
        acc[6] = fmaf(w, bf_lo(s.w), acc[6]); acc[7] = fmaf(w, bf_hi(s.w), acc[7]);
        sw += w;
    }
    {
        const float* c = cadd + (size_t)(row / nPerGraph) * 512 + l * 8;
        #pragma unroll
        for (int i = 0; i < 8; i++) acc[i] = fmaf(sw, c[i], acc[i]);
    }
    uint4 o;
    o.x = packbf2(fmaxf(acc[0], 0.f), fmaxf(acc[1], 0.f));
    o.y = packbf2(fmaxf(acc[2], 0.f), fmaxf(acc[3], 0.f));
    o.z = packbf2(fmaxf(acc[4], 0.f), fmaxf(acc[5], 0.f));
    o.w = packbf2(fmaxf(acc[6], 0.f), fmaxf(acc[7], 0.f));
    ((uint4*)D)[(size_t)row * 64 + l] = o;
}

// ---------------- bf16 MFMA GEMM: C[M,512] = A[M,512] @ Wt^T ----------------
// LDS-FREE: the 16x16x32 A/B fragment per lane is 8 contiguous K-elements of one row
// (verified identical to what the proven LDS round-trip delivered), so each lane loads
// its fragments DIRECTLY from global as 16B dwordx4. No barriers, no LDS, no waitcnt
// asm — correctness is pure dataflow (compiler inserts waits before use). In-block
// A-reuse hits L1; cross-bn reuse hits XCD L2 (same swizzle as before); B (512 KB) is
// L2-resident. Ping-pong frag buffers are named (rule #20), loop fully unrolled.
// Epilogues: CMODE 0: C bf16. CMODE 1: C fp32 += cadd[g], leaky. CMODE 2: C bf16 =
// relu(acc + bias[col]); root row saved pre-relu fp32 -> hroot.
template<int CMODE>
__global__ __launch_bounds__(256, 3) void gemm_mfma_kernel(
    const ushort16* __restrict__ Ab, const ushort16* __restrict__ Bt,
    void* __restrict__ Cvoid, const float* __restrict__ cadd,
    const int* __restrict__ root_idx, float* __restrict__ hroot, int nPerGraph)
{
    const int t = threadIdx.x;
    const int id = blockIdx.x;
    const int bm = (id >> 5) * 8 + (id & 7);
    const int bn = (id >> 3) & 3;
    const int lane = t & 63, wave = t >> 6;
    const int wm = wave >> 1, wn = wave & 1;
    const int quad = lane >> 4, l16 = lane & 15;

    // per-lane fragment base pointers: row = tile_row + l16, k-chunk = quad*8
    const ushort16* Aptr = Ab + (size_t)(bm * 128 + wm * 64 + l16) * 512 + quad * 8;
    const ushort16* Bptr = Bt + (size_t)(bn * 128 + wn * 64 + l16) * 512 + quad * 8;

    f32x4 acc[4][4];
    #pragma unroll
    for (int i = 0; i < 4; i++)
        #pragma unroll
        for (int j = 0; j < 4; j++)
            acc[i][j] = (f32x4){0.f, 0.f, 0.f, 0.f};

    auto loadT = [&](int k0, short8* a, short8* b) {
        #pragma unroll
        for (int i = 0; i < 4; i++)
            a[i] = *(const short8*)(Aptr + (size_t)i * 16 * 512 + k0);
        #pragma unroll
        for (int i = 0; i < 4; i++)
            b[i] = *(const short8*)(Bptr + (size_t)i * 16 * 512 + k0);
    };

    short8 aA[4], bA[4], aB[4], bB[4];   // named ping-pong buffers (static indexing)
    loadT(0, aA, bA);

    #pragma unroll
    for (int kt = 0; kt < 16; kt++) {
        short8* ac = (kt & 1) ? aB : aA;
        short8* bc = (kt & 1) ? bB : bA;
        short8* an = (kt & 1) ? aA : aB;
        short8* bn_ = (kt & 1) ? bA : bB;
        if (kt < 15) loadT((kt + 1) * 32, an, bn_);
        #pragma unroll
        for (int mi = 0; mi < 4; mi++)
            #pragma unroll
            for (int ni = 0; ni < 4; ni++)
                acc[mi][ni] = __builtin_amdgcn_mfma_f32_16x16x32_bf16(
                    ac[mi], bc[ni], acc[mi][ni], 0, 0, 0);
    }

    if (CMODE == 0) {
        ushort16* C2 = (ushort16*)Cvoid;
        #pragma unroll
        for (int ni = 0; ni < 4; ni++) {
            const int col = bn * 128 + wn * 64 + ni * 16 + l16;
            #pragma unroll
            for (int mi = 0; mi < 4; mi++) {
                const int row0 = bm * 128 + wm * 64 + mi * 16 + quad * 4;
                #pragma unroll
                for (int r = 0; r < 4; r++)
                    C2[(size_t)(row0 + r) * 512 + col] = f2bf(acc[mi][ni][r]);
            }
        }
    } else if (CMODE == 1) {
        float* Cf = (float*)Cvoid;
        const int g = (bm * 128) / nPerGraph;
        #pragma unroll
        for (int ni = 0; ni < 4; ni++) {
            const int col = bn * 128 + wn * 64 + ni * 16 + l16;
            const float cv = cadd[(size_t)g * 512 + col];
            #pragma unroll
            for (int mi = 0; mi < 4; mi++) {
                const int row0 = bm * 128 + wm * 64 + mi * 16 + quad * 4;
                #pragma unroll
                for (int r = 0; r < 4; r++) {
                    float v = acc[mi][ni][r] + cv;
                    v = v > 0.f ? v : 0.01f * v;
                    Cf[(size_t)(row0 + r) * 512 + col] = v;
                }
            }
        }
    } else {   // CMODE == 2: h1 epilogue — +bias, relu, root-row fp32 save
        ushort16* C2 = (ushort16*)Cvoid;
        const int g = (bm * 128) / nPerGraph;
        const int root = root_idx[g];
        #pragma unroll
        for (int ni = 0; ni < 4; ni++) {
            const int col = bn * 128 + wn * 64 + ni * 16 + l16;
            const float bv = cadd[col];
            #pragma unroll
            for (int mi = 0; mi < 4; mi++) {
                const int row0 = bm * 128 + wm * 64 + mi * 16 + quad * 4;
                #pragma unroll
                for (int r = 0; r < 4; r++) {
                    float v = acc[mi][ni][r] + bv;
                    if (row0 + r == root)
                        hroot[(size_t)g * 512 + col] = v;   // raw (pre-relu) fp32
                    C2[(size_t)(row0 + r) * 512 + col] = f2bf(fmaxf(v, 0.f));
                }
            }
        }
    }
}

// ---------------- per-graph root vectors (fp32, small) ----------------
__global__ __launch_bounds__(256) void rootvec_kernel(
    const float* __restrict__ X, const float* __restrict__ hroot,
    const int* __restrict__ root_idx,
    const float* __restrict__ W2full, const float* __restrict__ Wlfull,
    const float* __restrict__ bl,
    float* __restrict__ c2, float* __restrict__ c3)
{
    __shared__ float xs[512];
    __shared__ float red[4][64];
    const int g = blockIdx.x, which = blockIdx.y, chunk = blockIdx.z;
    const int t = threadIdx.x;
    const float* src = which ? (hroot + (size_t)g * 512)
                             : (X + (size_t)root_idx[g] * 512);
    const float* W = (which ? Wlfull : W2full) + 512 * 512;

    for (int k = t; k < 512; k += 256) {
        float v = src[k];
        if (which == 0) v = fmaxf(v, 0.f);
        xs[k] = v;
    }
    __syncthreads();

    const int col = chunk * 64 + (t & 63), kg = t >> 6;
    float acc = 0.f;
    #pragma unroll 4
    for (int k = kg * 128; k < kg * 128 + 128; k++)
        acc = fmaf(xs[k], W[(size_t)k * 512 + col], acc);
    red[kg][t & 63] = acc;
    __syncthreads();
    if (t < 64) {
        float s = red[0][t] + red[1][t] + red[2][t] + red[3][t];
        int c = chunk * 64 + t;
        if (which) c3[(size_t)g * 512 + c] = s + bl[c];
        else       c2[(size_t)g * 512 + c] = s;
    }
}

extern "C" void kernel_launch(void* const* d_in, const int* in_sizes, int n_in,
                              void* d_out, int out_size, void* d_ws, size_t ws_size,
                              hipStream_t stream)
{
    const float* X        = (const float*)d_in[0];
    const int*   adjs     = (const int*)d_in[1];
    const float* vals     = (const float*)d_in[2];
    const int*   root_idx = (const int*)d_in[3];
    const float* W1       = (const float*)d_in[6];
    const float* b1       = (const float*)d_in[7];
    const float* W2       = (const float*)d_in[8];
    const float* b2       = (const float*)d_in[9];
    const float* Wl       = (const float*)d_in[10];
    const float* bl       = (const float*)d_in[11];
    float* out = (float*)d_out;

    const int M    = in_sizes[0] / 512;   // 65536 nodes total
    const int Etot = in_sizes[2];         // 65536 edges total
    const int Bg   = in_sizes[3];         // 16 graphs
    const int N    = M / Bg;              // 4096 nodes/graph

    // workspace layout
    ushort16* bufS  = (ushort16*)d_ws;                     // aggX / s2 (bf16)
    ushort16* bufH  = bufS + (size_t)M * 512;              // relu(h1) / relu(agg2) (bf16)
    ushort16* Wt    = bufH + (size_t)M * 512;              // 3 x 512x512 bf16 [n][k]
    float*    c2    = (float*)(Wt + (size_t)3 * 512 * 512);
    float*    c3    = c2 + (size_t)Bg * 512;
    float*    hroot = c3 + (size_t)Bg * 512;               // raw fp32 h1 root rows
    int*      deg    = (int*)(hroot + (size_t)Bg * 512);
    int*      cursor = deg + M;
    int*      offs   = cursor + M;
    int*      bsum   = offs + M;
    int*      ecol   = bsum + 256;
    float*    ew     = (float*)(ecol + Etot);

    const int* rows = adjs;          // adjs[0] = src (segment target)
    const int* cols = adjs + Etot;   // adjs[1] = dst (gather source)

    const int eBlocks = (Etot + 255) / 256;
    dim3 gemmGrid((M / 128) * 4);    // 1-D, XCD-swizzled inside kernel

    // --- weights -> bf16 transposed ---
    convertW_kernel<<<dim3(16, 16, 3), 256, 0, stream>>>(W1, W2, Wl, Wt);

    // --- CSR build ---
    zero_kernel<<<(2 * M + 255) / 256, 256, 0, stream>>>(deg, 2 * M);   // deg + cursor
    hist_kernel<<<eBlocks, 256, 0, stream>>>(rows, deg, Etot);
    scan_block_kernel<<<M / 256, 256, 0, stream>>>(deg, offs, bsum);
    scan_top_kernel<<<1, 256, 0, stream>>>(bsum);
    scan_add_kernel<<<M / 256, 256, 0, stream>>>(offs, bsum);
    fill_kernel<<<eBlocks, 256, 0, stream>>>(rows, cols, vals, offs, cursor, ecol, ew, Etot);

    // --- 1a. aggX = gather(X) -> bufS (bf16). Linearity: Agg(X@W1) == (AggX)@W1 ---
    gatherX_kernel<<<M / 4, 256, 0, stream>>>(X, bufS, offs, deg, ecol, ew);
    // --- 1b. bufH = relu(b1 + aggX @ W1); hroot = raw fp32 root rows (pre-relu) ---
    gemm_mfma_kernel<2><<<gemmGrid, 256, 0, stream>>>(bufS, Wt, bufH, b1,
                                                      root_idx, hroot, N);
    // --- 2. root vectors: c2 (from X), c3 (from hroot) ---
    rootvec_kernel<<<dim3(Bg, 2, 8), 256, 0, stream>>>(X, hroot, root_idx, W2, Wl, bl, c2, c3);
    // --- 3. s2 = relu(h1) @ W2a -> bufS ---
    gemm_mfma_kernel<0><<<gemmGrid, 256, 0, stream>>>(bufH, Wt + (size_t)512 * 512, bufS,
                                                      (const float*)nullptr,
                                                      (const int*)nullptr, (float*)nullptr, N);
    // --- 4. bufH = relu(b2 + sw*c2[g] + gather(w * s2[col])) ---
    gather_kernel<<<M / 4, 256, 0, stream>>>(bufS, bufH, offs, deg, ecol, ew, b2, c2, N);
    // --- 5. out = leaky(relu(agg2) @ Wla + c3[g]) -> d_out (fp32) ---
    gemm_mfma_kernel<1><<<gemmGrid, 256, 0, stream>>>(bufH, Wt + (size_t)2 * 512 * 512,
                                                      out, c3,
                                                      (const int*)nullptr, (float*)nullptr, N);
}

// Round 8
// 478.229 us; speedup vs baseline: 1.4466x; 1.4466x over previous
//
#include <hip/hip_runtime.h>
#include <hip/hip_bf16.h>
#include <cstdint>

typedef unsigned int uint32;
typedef unsigned short ushort16;
typedef __attribute__((ext_vector_type(8))) short short8;   // 8 bf16 (4 VGPRs)
typedef __attribute__((ext_vector_type(4))) float f32x4;

// fp32 -> bf16 round-to-nearest-even (finite inputs)
__device__ __forceinline__ ushort16 f2bf(float f) {
    uint32 u = __float_as_uint(f);
    u += 0x7fffu + ((u >> 16) & 1u);
    return (ushort16)(u >> 16);
}
__device__ __forceinline__ uint32 packbf2(float lo, float hi) {
    return (uint32)f2bf(lo) | ((uint32)f2bf(hi) << 16);
}
__device__ __forceinline__ float bf_lo(uint32 u) { return __uint_as_float(u << 16); }
__device__ __forceinline__ float bf_hi(uint32 u) { return __uint_as_float(u & 0xffff0000u); }

// async global->LDS, 16B per lane; LDS dest = wave-uniform base + lane*16
__device__ __forceinline__ void gload_lds16(const void* g, void* l) {
    __builtin_amdgcn_global_load_lds(
        (const __attribute__((address_space(1))) uint32*)g,
        (__attribute__((address_space(3))) uint32*)l, 16, 0, 0);
}

// ---------------- weight convert + transpose: Wt[n][k] = bf16(W[k][n]) ----------------
__global__ __launch_bounds__(256) void convertW_kernel(
    const float* __restrict__ W1, const float* __restrict__ W2,
    const float* __restrict__ Wl, ushort16* __restrict__ Wt)
{
    const float* src = blockIdx.z == 0 ? W1 : (blockIdx.z == 1 ? W2 : Wl);
    ushort16* dst = Wt + (size_t)blockIdx.z * 512 * 512;
    __shared__ ushort16 tile[32][33];
    const int n0 = blockIdx.x * 32, k0 = blockIdx.y * 32;
    const int tx = threadIdx.x & 31, ty = threadIdx.x >> 5;
    #pragma unroll
    for (int j = 0; j < 32; j += 8)
        tile[ty + j][tx] = f2bf(src[(size_t)(k0 + ty + j) * 512 + n0 + tx]);
    __syncthreads();
    #pragma unroll
    for (int j = 0; j < 32; j += 8)
        dst[(size_t)(n0 + ty + j) * 512 + k0 + tx] = tile[tx][ty + j];
}

// ---------------- CSR build ----------------
__global__ __launch_bounds__(256) void zero_kernel(int* __restrict__ p, int n) {
    int i = blockIdx.x * 256 + threadIdx.x;
    if (i < n) p[i] = 0;
}
__global__ __launch_bounds__(256) void hist_kernel(
    const int* __restrict__ rows, int* __restrict__ deg, int E)
{
    int e = blockIdx.x * 256 + threadIdx.x;
    if (e < E) atomicAdd(&deg[rows[e]], 1);
}
__global__ __launch_bounds__(256) void scan_block_kernel(
    const int* __restrict__ deg, int* __restrict__ offs, int* __restrict__ bsum)
{
    __shared__ int s[256];
    const int t = threadIdx.x, i = blockIdx.x * 256 + t;
    int v = deg[i];
    s[t] = v; __syncthreads();
    for (int off = 1; off < 256; off <<= 1) {
        int x = (t >= off) ? s[t - off] : 0;
        __syncthreads();
        s[t] += x;
        __syncthreads();
    }
    offs[i] = s[t] - v;
    if (t == 255) bsum[blockIdx.x] = s[t];
}
__global__ __launch_bounds__(256) void scan_top_kernel(int* __restrict__ bsum)
{
    __shared__ int s[256];
    const int t = threadIdx.x;
    int v = bsum[t];
    s[t] = v; __syncthreads();
    for (int off = 1; off < 256; off <<= 1) {
        int x = (t >= off) ? s[t - off] : 0;
        __syncthreads();
        s[t] += x;
        __syncthreads();
    }
    bsum[t] = s[t] - v;
}
__global__ __launch_bounds__(256) void scan_add_kernel(
    int* __restrict__ offs, const int* __restrict__ bsum)
{
    offs[blockIdx.x * 256 + threadIdx.x] += bsum[blockIdx.x];
}
__global__ __launch_bounds__(256) void fill_kernel(
    const int* __restrict__ rows, const int* __restrict__ cols,
    const float* __restrict__ vals, const int* __restrict__ offs,
    int* __restrict__ cursor, int* __restrict__ ecol, float* __restrict__ ew, int E)
{
    int e = blockIdx.x * 256 + threadIdx.x;
    if (e >= E) return;
    int r = rows[e];
    int p = atomicAdd(&cursor[r], 1);
    int s = offs[r] + p;
    ecol[s] = cols[e];
    ew[s] = vals[e];
}

// ---- CSR gather on fp32 X -> bf16 aggX: D[row] = Σ w * X[col]  (no bias, no relu) ----
// Linearity: Agg(X@W1) == (Agg X)@W1, so layer-1 gathers BEFORE the GEMM.
__global__ __launch_bounds__(256) void gatherX_kernel(
    const float* __restrict__ X, ushort16* __restrict__ D,
    const int* __restrict__ offs, const int* __restrict__ deg,
    const int* __restrict__ ecol, const float* __restrict__ ew)
{
    const int wave = threadIdx.x >> 6, l = threadIdx.x & 63;
    const int row = blockIdx.x * 4 + wave;
    float acc[8];
    #pragma unroll
    for (int i = 0; i < 8; i++) acc[i] = 0.f;
    const int start = offs[row], d = deg[row];
    for (int j = 0; j < d; j++) {
        int col = ecol[start + j];
        float w = ew[start + j];
        const float4* xr = (const float4*)(X + (size_t)col * 512) + l * 2;
        float4 a = xr[0], b = xr[1];
        acc[0] = fmaf(w, a.x, acc[0]); acc[1] = fmaf(w, a.y, acc[1]);
        acc[2] = fmaf(w, a.z, acc[2]); acc[3] = fmaf(w, a.w, acc[3]);
        acc[4] = fmaf(w, b.x, acc[4]); acc[5] = fmaf(w, b.y, acc[5]);
        acc[6] = fmaf(w, b.z, acc[6]); acc[7] = fmaf(w, b.w, acc[7]);
    }
    uint4 o;
    o.x = packbf2(acc[0], acc[1]);
    o.y = packbf2(acc[2], acc[3]);
    o.z = packbf2(acc[4], acc[5]);
    o.w = packbf2(acc[6], acc[7]);
    ((uint4*)D)[(size_t)row * 64 + l] = o;
}

// ---- CSR gather (bf16 in/out, fp32 accum): D[row]=relu(bias + Σ w*S[col] + Σw*c[g]) ----
__global__ __launch_bounds__(256) void gather_kernel(
    const ushort16* __restrict__ S, ushort16* __restrict__ D,
    const int* __restrict__ offs, const int* __restrict__ deg,
    const int* __restrict__ ecol, const float* __restrict__ ew,
    const float* __restrict__ bias, const float* __restrict__ cadd, int nPerGraph)
{
    const int wave = threadIdx.x >> 6, l = threadIdx.x & 63;
    const int row = blockIdx.x * 4 + wave;
    const uint4* S4 = (const uint4*)S;     // 64 x uint4 per row
    float acc[8];
    {
        float4 b0 = ((const float4*)bias)[l * 2];
        float4 b1 = ((const float4*)bias)[l * 2 + 1];
        acc[0] = b0.x; acc[1] = b0.y; acc[2] = b0.z; acc[3] = b0.w;
        acc[4] = b1.x; acc[5] = b1.y; acc[6] = b1.z; acc[7] = b1.w;
    }
    const int start = offs[row], d = deg[row];
    float sw = 0.f;
    for (int j = 0; j < d; j++) {
        int col = ecol[start + j];
        float w = ew[start + j];
        uint4 s = S4[(size_t)col * 64 + l];
        acc[0] = fmaf(w, bf_lo(s.x), acc[0]); acc[1] = fmaf(w, bf_hi(s.x), acc[1]);
        acc[2] = fmaf(w, bf_lo(s.y), acc[2]); acc[3] = fmaf(w, bf_hi(s.y), acc[3]);
        acc[4] = fmaf(w, bf_lo(s.z), acc[4]); acc[5] = fmaf(w, bf_hi(s.z), acc[5]);
        acc[6] = fmaf(w, bf_lo(s.w), acc[6]); acc[7] = fmaf(w, bf_hi(s.w), acc[7]);
        sw += w;
    }
    {
        const float* c = cadd + (size_t)(row / nPerGraph) * 512 + l * 8;
        #pragma unroll
        for (int i = 0; i < 8; i++) acc[i] = fmaf(sw, c[i], acc[i]);
    }
    uint4 o;
    o.x = packbf2(fmaxf(acc[0], 0.f), fmaxf(acc[1], 0.f));
    o.y = packbf2(fmaxf(acc[2], 0.f), fmaxf(acc[3], 0.f));
    o.z = packbf2(fmaxf(acc[4], 0.f), fmaxf(acc[5], 0.f));
    o.w = packbf2(fmaxf(acc[6], 0.f), fmaxf(acc[7], 0.f));
    ((uint4*)D)[(size_t)row * 64 + l] = o;
}

// ---------------- bf16 MFMA GEMM: C[M,512] = A[M,512] @ Wt^T ----------------
// Proven counted-vmcnt 2-buffer template at tile 256x128, 512 threads / 8 waves (4x2).
// Per stage per lane: 2 A-glds + 1 B-gld = 3 vm ops -> steady s_waitcnt vmcnt(3)
// (stage kt+1 in flight), vmcnt(0) only at the last tile. Same barrier/read/write
// structure and chunk-XOR swizzle as the r2/r4/r5/r6-proven kernels; only the tile
// geometry and wait literals changed. LDS 48KB -> 3 blocks/CU (24 waves/CU) for
// barrier-stall coverage. Fully unrolled (K=512, 16 tiles).
// Epilogues: CMODE 0: C bf16. CMODE 1: C fp32 += cadd[g], leaky. CMODE 2: C bf16 =
// relu(acc + bias[col]); root row saved pre-relu fp32 -> hroot.
template<int CMODE>
__global__ __launch_bounds__(512) void gemm_mfma_kernel(
    const ushort16* __restrict__ Ab, const ushort16* __restrict__ Bt,
    void* __restrict__ Cvoid, const float* __restrict__ cadd,
    const int* __restrict__ root_idx, float* __restrict__ hroot, int nPerGraph)
{
    __shared__ __align__(16) ushort16 As[2][256 * 32];
    __shared__ __align__(16) ushort16 Bs[2][128 * 32];

    const int t = threadIdx.x;
    const int id = blockIdx.x;
    const int bm = (id >> 5) * 8 + (id & 7);   // 0..255 (M/256 tiles), XCD-swizzled
    const int bn = (id >> 3) & 3;              // 0..3   (N/128 tiles)
    const int lane = t & 63, wave = t >> 6;    // wave 0..7
    const int wm = wave >> 1, wn = wave & 1;   // 4x2 wave grid: 64-row x 64-col each
    const int quad = lane >> 4, l16 = lane & 15;
    const int grow = lane >> 2;                         // row within 16-row segment
    const int gkc = (((lane & 3) ^ ((grow >> 1) & 3))) * 8;   // swizzled k-chunk (elems)
    const int swz = (l16 >> 1) & 3;                     // read-side chunk XOR

    const ushort16* Bbase = Bt + (size_t)(bn * 128) * 512;

    f32x4 acc[4][4];
    #pragma unroll
    for (int i = 0; i < 4; i++)
        #pragma unroll
        for (int j = 0; j < 4; j++)
            acc[i][j] = (f32x4){0.f, 0.f, 0.f, 0.f};

    // stage one 256x32 A-tile + 128x32 B-tile into buffer `buf` (3 glds per lane)
    auto stage = [&](int k0, int buf) {
        #pragma unroll
        for (int j = 0; j < 2; j++) {
            int seg = wave * 2 + j;            // 16 A-segments of 16 rows
            gload_lds16(Ab + (size_t)(bm * 256 + seg * 16 + grow) * 512 + k0 + gkc,
                        &As[buf][seg * 512 + lane * 8]);
        }
        {
            int seg = wave;                    // 8 B-segments of 16 rows
            gload_lds16(Bbase + (size_t)(seg * 16 + grow) * 512 + k0 + gkc,
                        &Bs[buf][seg * 512 + lane * 8]);
        }
    };

    // prologue: 2 tiles in flight
    stage(0, 0);
    stage(32, 1);

    #pragma unroll
    for (int kt = 0; kt < 16; kt++) {
        const int buf = kt & 1;
        // wait for stage(kt); stage(kt+1)'s 3 loads may stay in flight
        if (kt < 15) { asm volatile("s_waitcnt vmcnt(3)" ::: "memory"); }
        else         { asm volatile("s_waitcnt vmcnt(0)" ::: "memory"); }
        __builtin_amdgcn_sched_barrier(0);
        __builtin_amdgcn_s_barrier();          // all waves: stage(kt) landed
        __builtin_amdgcn_sched_barrier(0);

        short8 af[4], bfr[4];
        #pragma unroll
        for (int mi = 0; mi < 4; mi++)
            af[mi] = *(const short8*)
                &As[buf][(wm * 64 + mi * 16 + l16) * 32 + (quad ^ swz) * 8];
        #pragma unroll
        for (int ni = 0; ni < 4; ni++)
            bfr[ni] = *(const short8*)
                &Bs[buf][(wn * 64 + ni * 16 + l16) * 32 + (quad ^ swz) * 8];

        asm volatile("s_waitcnt lgkmcnt(0)" ::: "memory");
        __builtin_amdgcn_sched_barrier(0);
        __builtin_amdgcn_s_barrier();          // all waves done reading buf -> reusable
        __builtin_amdgcn_sched_barrier(0);

        if (kt + 2 < 16) stage((kt + 2) * 32, buf);   // refill freed buffer
        __builtin_amdgcn_sched_barrier(0);

        __builtin_amdgcn_s_setprio(1);
        #pragma unroll
        for (int mi = 0; mi < 4; mi++)
            #pragma unroll
            for (int ni = 0; ni < 4; ni++)
                acc[mi][ni] = __builtin_amdgcn_mfma_f32_16x16x32_bf16(
                    af[mi], bfr[ni], acc[mi][ni], 0, 0, 0);
        __builtin_amdgcn_s_setprio(0);
    }

    if (CMODE == 0) {
        ushort16* C2 = (ushort16*)Cvoid;
        #pragma unroll
        for (int ni = 0; ni < 4; ni++) {
            const int col = bn * 128 + wn * 64 + ni * 16 + l16;
            #pragma unroll
            for (int mi = 0; mi < 4; mi++) {
                const int row0 = bm * 256 + wm * 64 + mi * 16 + quad * 4;
                #pragma unroll
                for (int r = 0; r < 4; r++)
                    C2[(size_t)(row0 + r) * 512 + col] = f2bf(acc[mi][ni][r]);
            }
        }
    } else if (CMODE == 1) {
        float* Cf = (float*)Cvoid;
        const int g = (bm * 256) / nPerGraph;
        #pragma unroll
        for (int ni = 0; ni < 4; ni++) {
            const int col = bn * 128 + wn * 64 + ni * 16 + l16;
            const float cv = cadd[(size_t)g * 512 + col];
            #pragma unroll
            for (int mi = 0; mi < 4; mi++) {
                const int row0 = bm * 256 + wm * 64 + mi * 16 + quad * 4;
                #pragma unroll
                for (int r = 0; r < 4; r++) {
                    float v = acc[mi][ni][r] + cv;
                    v = v > 0.f ? v : 0.01f * v;
                    Cf[(size_t)(row0 + r) * 512 + col] = v;
                }
            }
        }
    } else {   // CMODE == 2: h1 epilogue — +bias, relu, root-row fp32 save
        ushort16* C2 = (ushort16*)Cvoid;
        const int g = (bm * 256) / nPerGraph;
        const int root = root_idx[g];
        #pragma unroll
        for (int ni = 0; ni < 4; ni++) {
            const int col = bn * 128 + wn * 64 + ni * 16 + l16;
            const float bv = cadd[col];
            #pragma unroll
            for (int mi = 0; mi < 4; mi++) {
                const int row0 = bm * 256 + wm * 64 + mi * 16 + quad * 4;
                #pragma unroll
                for (int r = 0; r < 4; r++) {
                    float v = acc[mi][ni][r] + bv;
                    if (row0 + r == root)
                        hroot[(size_t)g * 512 + col] = v;   // raw (pre-relu) fp32
                    C2[(size_t)(row0 + r) * 512 + col] = f2bf(fmaxf(v, 0.f));
                }
            }
        }
    }
}

// ---------------- per-graph root vectors (fp32, small) ----------------
__global__ __launch_bounds__(256) void rootvec_kernel(
    const float* __restrict__ X, const float* __restrict__ hroot,
    const int* __restrict__ root_idx,
    const float* __restrict__ W2full, const float* __restrict__ Wlfull,
    const float* __restrict__ bl,
    float* __restrict__ c2, float* __restrict__ c3)
{
    __shared__ float xs[512];
    __shared__ float red[4][64];
    const int g = blockIdx.x, which = blockIdx.y, chunk = blockIdx.z;
    const int t = threadIdx.x;
    const float* src = which ? (hroot + (size_t)g * 512)
                             : (X + (size_t)root_idx[g] * 512);
    const float* W = (which ? Wlfull : W2full) + 512 * 512;

    for (int k = t; k < 512; k += 256) {
        float v = src[k];
        if (which == 0) v = fmaxf(v, 0.f);
        xs[k] = v;
    }
    __syncthreads();

    const int col = chunk * 64 + (t & 63), kg = t >> 6;
    float acc = 0.f;
    #pragma unroll 4
    for (int k = kg * 128; k < kg * 128 + 128; k++)
        acc = fmaf(xs[k], W[(size_t)k * 512 + col], acc);
    red[kg][t & 63] = acc;
    __syncthreads();
    if (t < 64) {
        float s = red[0][t] + red[1][t] + red[2][t] + red[3][t];
        int c = chunk * 64 + t;
        if (which) c3[(size_t)g * 512 + c] = s + bl[c];
        else       c2[(size_t)g * 512 + c] = s;
    }
}

extern "C" void kernel_launch(void* const* d_in, const int* in_sizes, int n_in,
                              void* d_out, int out_size, void* d_ws, size_t ws_size,
                              hipStream_t stream)
{
    const float* X        = (const float*)d_in[0];
    const int*   adjs     = (const int*)d_in[1];
    const float* vals     = (const float*)d_in[2];
    const int*   root_idx = (const int*)d_in[3];
    const float* W1       = (const float*)d_in[6];
    const float* b1       = (const float*)d_in[7];
    const float* W2       = (const float*)d_in[8];
    const float* b2       = (const float*)d_in[9];
    const float* Wl       = (const float*)d_in[10];
    const float* bl       = (const float*)d_in[11];
    float* out = (float*)d_out;

    const int M    = in_sizes[0] / 512;   // 65536 nodes total
    const int Etot = in_sizes[2];         // 65536 edges total
    const int Bg   = in_sizes[3];         // 16 graphs
    const int N    = M / Bg;              // 4096 nodes/graph

    // workspace layout
    ushort16* bufS  = (ushort16*)d_ws;                     // aggX / s2 (bf16)
    ushort16* bufH  = bufS + (size_t)M * 512;              // relu(h1) / relu(agg2) (bf16)
    ushort16* Wt    = bufH + (size_t)M * 512;              // 3 x 512x512 bf16 [n][k]
    float*    c2    = (float*)(Wt + (size_t)3 * 512 * 512);
    float*    c3    = c2 + (size_t)Bg * 512;
    float*    hroot = c3 + (size_t)Bg * 512;               // raw fp32 h1 root rows
    int*      deg    = (int*)(hroot + (size_t)Bg * 512);
    int*      cursor = deg + M;
    int*      offs   = cursor + M;
    int*      bsum   = offs + M;
    int*      ecol   = bsum + 256;
    float*    ew     = (float*)(ecol + Etot);

    const int* rows = adjs;          // adjs[0] = src (segment target)
    const int* cols = adjs + Etot;   // adjs[1] = dst (gather source)

    const int eBlocks = (Etot + 255) / 256;
    dim3 gemmGrid((M / 256) * 4);    // 1024 blocks, XCD-swizzled inside kernel

    // --- weights -> bf16 transposed ---
    convertW_kernel<<<dim3(16, 16, 3), 256, 0, stream>>>(W1, W2, Wl, Wt);

    // --- CSR build ---
    zero_kernel<<<(2 * M + 255) / 256, 256, 0, stream>>>(deg, 2 * M);   // deg + cursor
    hist_kernel<<<eBlocks, 256, 0, stream>>>(rows, deg, Etot);
    scan_block_kernel<<<M / 256, 256, 0, stream>>>(deg, offs, bsum);
    scan_top_kernel<<<1, 256, 0, stream>>>(bsum);
    scan_add_kernel<<<M / 256, 256, 0, stream>>>(offs, bsum);
    fill_kernel<<<eBlocks, 256, 0, stream>>>(rows, cols, vals, offs, cursor, ecol, ew, Etot);

    // --- 1a. aggX = gather(X) -> bufS (bf16). Linearity: Agg(X@W1) == (AggX)@W1 ---
    gatherX_kernel<<<M / 4, 256, 0, stream>>>(X, bufS, offs, deg, ecol, ew);
    // --- 1b. bufH = relu(b1 + aggX @ W1); hroot = raw fp32 root rows (pre-relu) ---
    gemm_mfma_kernel<2><<<gemmGrid, 512, 0, stream>>>(bufS, Wt, bufH, b1,
                                                      root_idx, hroot, N);
    // --- 2. root vectors: c2 (from X), c3 (from hroot) ---
    rootvec_kernel<<<dim3(Bg, 2, 8), 256, 0, stream>>>(X, hroot, root_idx, W2, Wl, bl, c2, c3);
    // --- 3. s2 = relu(h1) @ W2a -> bufS ---
    gemm_mfma_kernel<0><<<gemmGrid, 512, 0, stream>>>(bufH, Wt + (size_t)512 * 512, bufS,
                                                      (const float*)nullptr,
                                                      (const int*)nullptr, (float*)nullptr, N);
    // --- 4. bufH = relu(b2 + sw*c2[g] + gather(w * s2[col])) ---
    gather_kernel<<<M / 4, 256, 0, stream>>>(bufS, bufH, offs, deg, ecol, ew, b2, c2, N);
    // --- 5. out = leaky(relu(agg2) @ Wla + c3[g]) -> d_out (fp32) ---
    gemm_mfma_kernel<1><<<gemmGrid, 512, 0, stream>>>(bufH, Wt + (size_t)2 * 512 * 512,
                                                      out, c3,
                                                      (const int*)nullptr, (float*)nullptr, N);
}